// Round 6
// baseline (747.758 us; speedup 1.0000x reference)
//
#include <hip/hip_runtime.h>
#include <hip/hip_bf16.h>
#include <math.h>

#define HW 16384      // 128*128
#define BATCH 4
#define KIDS 20

using short8 = __attribute__((ext_vector_type(8))) short;  // 8 bf16 = 16B
using f32x4  = __attribute__((ext_vector_type(4))) float;

__device__ __forceinline__ unsigned short bfbits(float f) {
  __hip_bfloat16 h = __float2bfloat16(f);
  return *(unsigned short*)&h;
}

// async global -> LDS, 16B per lane, wave-uniform LDS base + lane*16
__device__ __forceinline__ void gload_lds16(const void* g, void* l) {
  __builtin_amdgcn_global_load_lds(
      (const __attribute__((address_space(1))) void*)g,
      (__attribute__((address_space(3))) void*)l, 16, 0, 0);
}

__global__ __launch_bounds__(256) void zero_k(float* __restrict__ p, int n) {
  int i = blockIdx.x*256 + threadIdx.x;
  if (i < n) p[i] = 0.f;
}

// ---- x: fp32 NCHW [4][512][128][128] -> bf16 NHWC [4][16384][512] ----------
__global__ __launch_bounds__(256) void x_to_nhwc_k(const float* __restrict__ in,
                                                   __hip_bfloat16* __restrict__ out)
{
  __shared__ float tile[32][65];
  int t = blockIdx.x;
  const int pxt = t & 255; t >>= 8;
  const int ct  = t & 15;  t >>= 4;
  const int b   = t;
  const int tid = threadIdx.x;
  #pragma unroll
  for (int it = 0; it < 8; ++it) {
    int idx = tid + it*256;
    int px_l = idx & 63, c_l = idx >> 6;
    tile[c_l][px_l] = in[((size_t)(b*512 + ct*32 + c_l))*HW + pxt*64 + px_l];
  }
  __syncthreads();
  #pragma unroll
  for (int it = 0; it < 4; ++it) {
    int idx = tid + it*256;
    int c2 = idx & 15, px_l = idx >> 4;
    unsigned u = ((unsigned)bfbits(tile[c2*2+1][px_l]) << 16) | bfbits(tile[c2*2][px_l]);
    *(unsigned*)(out + ((size_t)(b*HW + pxt*64 + px_l))*512 + ct*32 + c2*2) = u;
  }
}

// ---- weights: fp32 [Co][Ci][3][3] -> bf16 [9][Co][Ci] ----------------------
template<int Co, int Ci>
__global__ __launch_bounds__(256) void pack_w_k(const float* __restrict__ w,
                                                __hip_bfloat16* __restrict__ out)
{
  const int i = blockIdx.x*256 + threadIdx.x;
  const int ci = i & (Ci-1);
  const int r  = i >> __builtin_ctz(Ci);
  const int co = r & (Co-1);
  const int t  = r >> __builtin_ctz(Co);
  out[i] = __float2bfloat16(w[((size_t)co*Ci + ci)*9 + t]);
}

// ---- implicit-GEMM conv3x3 via MFMA + fused GN partial stats ---------------
// 512-thread block = 8 waves: 2 rows x 2 px-halves x 2 co-halves.
// Block covers 2 rows x 128 px x WCO co (WCO = 2*MT*16).
//
// LDS layout is Q-MAJOR SEGMENTED: each 16-px (or 16-co) unit is a 1KB block
// [q:4][p16:16][16B] -- exactly the linear order global_load_lds writes
// (lane = q*16+p). At fixed q, consecutive lanes read consecutive 16B blocks
// -> every 8-lane phase covers all 8 bank-quads once: CONFLICT-FREE (the old
// px-stride-64B layout was a 4-way conflict; 18.9M conflict cycles).
// Input rows have 10 segs (slot = px+16; segs 0/9 are zeroed boundary pads),
// so all conv taps read with per-lane base VGPR + 16-bit immediate (0 VALU).
// OOB-row staging loads are redirected to a trash seg so EVERY wave issues
// exactly 4 input loads -> `s_waitcnt vmcnt(4)` provably drains all weight
// loads (each wave waits on its OWN counter; both 4- and 5-unit weight waves
// are covered).
// Next-tap operands are prefetched into registers, so each wave's ds_reads
// overlap its own MFMAs instead of alternating batches.
template<int Ci, int Co, int CPG, int MT>
__global__ __launch_bounds__(512, 2) void conv_mfma_k(
    const __hip_bfloat16* __restrict__ xin,  // NHWC bf16 [4][16384][Ci]
    const __hip_bfloat16* __restrict__ wpk,  // [9][Co][Ci] bf16
    const float* __restrict__ bias,
    float* __restrict__ out,                 // NHWC fp32 [4][16384][Co]
    float* __restrict__ partS, float* __restrict__ partSS)
{
  constexpr int NT  = 4;
  constexpr int RG  = 64;
  constexpr int NC  = Ci/32;           // ci chunks
  constexpr int NGW = (MT*16)/CPG;     // GN groups per wave's co range
  constexpr int WCO = 2*MT*16;         // co per block
  constexpr int WSEG = WCO/16;         // 16-co units per tap
  constexpr int IBs = 4*10*512;        // shorts per input buffer (4 rows x 10 segs)
  constexpr int WLs = 9*WSEG*512;      // weight shorts per chunk
  __shared__ __align__(16) short lds[2*IBs + WLs + 512];
  short* const wlds  = lds + 2*IBs;
  short* const trash = lds + 2*IBs + WLs;

  const int b  = blockIdx.x / RG;
  const int r0 = (blockIdx.x % RG) * 2;
  const int co0 = blockIdx.y * WCO;
  const int tid = threadIdx.x;
  const int wave = tid >> 6, lane = tid & 63;
  const int row_w = wave & 1;
  const int pw    = (wave >> 1) & 1;
  const int coh   = wave >> 2;
  const int co_w  = co0 + coh*MT*16;
  const int y = r0 + row_w;
  const int lr = lane & 15, q = lane >> 4;
  const int ls = lane & 15, lq = lane >> 4;   // staging: lane = lq*16 + ls

  // zero boundary pad segs (0 and 9) of each row, both buffers
  {
    short8 z = {0,0,0,0,0,0,0,0};
    for (int i = tid; i < 1024; i += 512) {
      int u = i >> 6, m = i & 63;
      int buf = u >> 3, r = (u >> 1) & 3, side = u & 1;
      *((short8*)(lds + buf*IBs + r*5120 + side*9*512) + m) = z;
    }
    if (r0 == 0) {       // row 0 is OOB: keep fully zero
      for (int i = tid; i < 2*640; i += 512) {
        int buf = i / 640, m = i % 640;
        *((short8*)(lds + buf*IBs + 0*5120) + m) = z;
      }
    }
    if (r0 == 126) {     // row 3 is OOB
      for (int i = tid; i < 2*640; i += 512) {
        int buf = i / 640, m = i % 640;
        *((short8*)(lds + buf*IBs + 3*5120) + m) = z;
      }
    }
  }

  const size_t in_base = (size_t)b * HW * Ci;

  // input: 4 gload_lds per wave per chunk, ALWAYS issued (OOB -> trash)
  auto stage_i = [&](int buf, int ci0) {
    #pragma unroll
    for (int it = 0; it < 4; ++it) {
      int gi = wave*4 + it;
      int r = gi >> 3, sd = (gi & 7) + 1;     // dest seg 1..8
      int yy = r0 + r - 1;
      bool ok = (unsigned)yy < 128u;
      int yc = ok ? yy : 0;
      const __hip_bfloat16* src = xin + in_base
          + (size_t)(yc*128 + (sd-1)*16 + ls)*Ci + ci0 + lq*8;
      short* dst = ok ? (lds + buf*IBs + r*5120 + sd*512) : trash;
      gload_lds16(src, dst);
    }
  };
  // weights: unit u = t*WSEG+cs -> 1KB at wlds+u*512 shorts
  auto stage_w = [&](int ci0) {
    for (int u = wave; u < 9*WSEG; u += 8) {
      int t = u / WSEG, cs = u % WSEG;
      gload_lds16(wpk + ((size_t)(t*Co + co0 + cs*16 + ls))*Ci + ci0 + lq*8,
                  wlds + u*512);
    }
  };

  // per-lane ds_read bases (in shorts); all tap offsets become immediates
  int base_dx[3];
  #pragma unroll
  for (int dx = 0; dx < 3; ++dx) {
    int e = dx + 15 + lr;                    // slot = 16*(pw*4+nt) + e
    base_dx[dx] = row_w*5120 + pw*2048 + (e>>4)*512 + (e&15)*8 + q*128;
  }
  const int base_a = coh*MT*512 + q*128 + lr*8;

  f32x4 acc[MT][NT] = {};
  stage_i(0, 0);
  __syncthreads();                 // zeros visible + first input drained
  int cur = 0;
  for (int c = 0; c < NC; ++c) {
    const int ci0 = c*32;
    stage_w(ci0);                  // overwrites wlds (prev reads done: barrier)
    if (c+1 < NC) {
      stage_i(cur^1, ci0 + 32);    // newest 4 ops: keep flying under compute
      asm volatile("s_waitcnt vmcnt(4)" ::: "memory");
    } else {
      asm volatile("s_waitcnt vmcnt(0)" ::: "memory");
    }
    __builtin_amdgcn_s_barrier();  // raw: no auto vmcnt(0) drain
    __builtin_amdgcn_sched_barrier(0);
    const short* ib = lds + cur*IBs;

    short8 af[2][MT], bf[2][NT];
    #pragma unroll
    for (int mt = 0; mt < MT; ++mt)
      af[0][mt] = *(const short8*)(wlds + base_a + mt*512);
    #pragma unroll
    for (int nt = 0; nt < NT; ++nt)
      bf[0][nt] = *(const short8*)(ib + base_dx[0] + nt*512);

    #pragma unroll
    for (int t = 0; t < 9; ++t) {
      const int cb = t & 1, nb = cb ^ 1;
      if (t < 8) {                 // prefetch tap t+1 operands under tap-t MFMAs
        const int t1 = t + 1, dy1 = t1/3, dx1 = t1%3;
        const short* wt = wlds + t1*WSEG*512;
        #pragma unroll
        for (int mt = 0; mt < MT; ++mt)
          af[nb][mt] = *(const short8*)(wt + base_a + mt*512);
        #pragma unroll
        for (int nt = 0; nt < NT; ++nt)
          bf[nb][nt] = *(const short8*)(ib + base_dx[dx1] + dy1*5120 + nt*512);
      }
      #pragma unroll
      for (int mt = 0; mt < MT; ++mt)
        #pragma unroll
        for (int nt = 0; nt < NT; ++nt)
          acc[mt][nt] = __builtin_amdgcn_mfma_f32_16x16x32_bf16(
              af[cb][mt], bf[cb][nt], acc[mt][nt], 0, 0, 0);
    }
    __builtin_amdgcn_s_barrier();  // all waves done reading before overwrite
    cur ^= 1;
  }

  // epilogue: +bias, store, and accumulate GN partial stats
  float sg[NGW] = {}, ssg[NGW] = {};
  #pragma unroll
  for (int mt = 0; mt < MT; ++mt) {
    const int g = (mt*16) / CPG;
    #pragma unroll
    for (int nt = 0; nt < NT; ++nt) {
      int px = pw*64 + nt*16 + lr;
      int co = co_w + mt*16 + q*4;
      const float4 bv = *(const float4*)(bias + co);
      f32x4 v = acc[mt][nt];
      v[0] += bv.x; v[1] += bv.y; v[2] += bv.z; v[3] += bv.w;
      sg[g]  += v[0] + v[1] + v[2] + v[3];
      ssg[g] += v[0]*v[0] + v[1]*v[1] + v[2]*v[2] + v[3]*v[3];
      *(f32x4*)(out + ((size_t)(b*HW + y*128 + px))*Co + co) = v;
    }
  }
  const int bgbase = b*(Co/CPG) + co_w/CPG;
  #pragma unroll
  for (int g = 0; g < NGW; ++g) {
    float s = sg[g], ss = ssg[g];
    #pragma unroll
    for (int off = 32; off; off >>= 1) {
      s  += __shfl_xor(s, off);
      ss += __shfl_xor(ss, off);
    }
    if (lane == 0) {
      atomicAdd(&partS[bgbase + g], s);
      atomicAdd(&partSS[bgbase + g], ss);
    }
  }
}

// ---- GN finalize: mean / rsqrt(var) from atomic partials -------------------
__global__ void gn_final_k(const float* __restrict__ partS,
                           const float* __restrict__ partSS,
                           float* __restrict__ mv, int nbg, float inv_n)
{
  const int i = threadIdx.x;
  if (i < nbg) {
    float s = partS[i], ss = partSS[i];
    float mean = s*inv_n, var = ss*inv_n - mean*mean;
    mv[2*i] = mean; mv[2*i+1] = rsqrtf(var + 1e-5f);
  }
}

// ---- GN apply: normalize+affine+ReLU; emit bf16 (or fp32) NHWC -------------
template<int C, int CPG, bool BF16OUT>
__global__ __launch_bounds__(256) void gn_apply_k(const float* __restrict__ in,
    const float* __restrict__ mv, const float* __restrict__ gw,
    const float* __restrict__ gb, void* __restrict__ outp)
{
  constexpr int C4 = C/4;
  constexpr int G = C/CPG;
  const int i = blockIdx.x*256 + threadIdx.x;
  const int c4 = i & (C4-1);
  const int pxb = i >> __builtin_ctz(C4);
  const int b = pxb >> 14;
  const int c = c4*4;
  const int bg = b*G + c/CPG;
  const float mean = mv[2*bg], inv = mv[2*bg+1];
  float4 v = *((const float4*)in + i);
  const float4 w4 = *(const float4*)(gw + c);
  const float4 b4 = *(const float4*)(gb + c);
  float r0 = fmaxf((v.x-mean)*inv*w4.x + b4.x, 0.f);
  float r1 = fmaxf((v.y-mean)*inv*w4.y + b4.y, 0.f);
  float r2 = fmaxf((v.z-mean)*inv*w4.z + b4.z, 0.f);
  float r3 = fmaxf((v.w-mean)*inv*w4.w + b4.w, 0.f);
  if (BF16OUT) {
    uint2 o;
    o.x = ((unsigned)bfbits(r1) << 16) | bfbits(r0);
    o.y = ((unsigned)bfbits(r3) << 16) | bfbits(r2);
    *(uint2*)((__hip_bfloat16*)outp + (size_t)i*4) = o;
  } else {
    *((float4*)outp + i) = make_float4(r0,r1,r2,r3);
  }
}

// ---- pooling ---------------------------------------------------------------
__global__ __launch_bounds__(256) void pool_counts_k(
    const int* __restrict__ masks, float* __restrict__ counts)
{
  __shared__ int hist[KIDS];
  const int b = blockIdx.x;
  if (threadIdx.x < KIDS) hist[threadIdx.x] = 0;
  __syncthreads();
  for (int p = threadIdx.x; p < HW; p += 256) {
    const int m = masks[b*HW + p];
    if (m > 0) atomicAdd(&hist[m-1], 1);
  }
  __syncthreads();
  if (threadIdx.x < KIDS) counts[b*KIDS + threadIdx.x] = (float)hist[threadIdx.x];
}

__global__ __launch_bounds__(256) void pool_sums_k(const float* __restrict__ h3,
    const int* __restrict__ masks, float* __restrict__ sums)
{
  __shared__ float acc[KIDS*64];
  const int b = blockIdx.x >> 5, chunk = blockIdx.x & 31;
  const int tid = threadIdx.x;
  for (int j = tid; j < KIDS*64; j += 256) acc[j] = 0.f;
  __syncthreads();
  const int ch = tid & 63, pi = tid >> 6;
  const int p0 = chunk*512;
  for (int p = p0 + pi; p < p0 + 512; p += 4) {
    int m = masks[b*HW + p];
    if (m > 0) atomicAdd(&acc[(m-1)*64 + ch], h3[((size_t)(b*HW + p))*64 + ch]);
  }
  __syncthreads();
  for (int j = tid; j < KIDS*64; j += 256) atomicAdd(&sums[b*KIDS*64 + j], acc[j]);
}

// ---- heads: one wave per (b,k) ---------------------------------------------
__global__ __launch_bounds__(64) void heads_k(
    const float* __restrict__ sums, const float* __restrict__ counts,
    const float* __restrict__ wb, const float* __restrict__ bb,
    const float* __restrict__ wc, const float* __restrict__ bc,
    float* __restrict__ out)
{
  const int bk = blockIdx.x;
  const int c = threadIdx.x;
  const float pooled = sums[bk*64 + c] / (counts[bk] + 1e-6f);
  #pragma unroll
  for (int o = 0; o < 7; ++o) {
    float t = pooled * wb[o*64 + c];
    for (int off = 32; off > 0; off >>= 1) t += __shfl_down(t, off);
    if (c == 0) out[bk*7 + o] = t + bb[o];
  }
  float t = pooled * wc[c];
  for (int off = 32; off > 0; off >>= 1) t += __shfl_down(t, off);
  if (c == 0) out[BATCH*KIDS*7 + bk] = 1.f / (1.f + expf(-(t + bc[0])));
}

extern "C" void kernel_launch(void* const* d_in, const int* in_sizes, int n_in,
                              void* d_out, int out_size, void* d_ws, size_t ws_size,
                              hipStream_t stream)
{
  const float* x     = (const float*)d_in[0];
  const int*   masks = (const int*)  d_in[1];
  const float* w1 = (const float*)d_in[2];
  const float* b1 = (const float*)d_in[3];
  const float* g1w= (const float*)d_in[4];
  const float* g1b= (const float*)d_in[5];
  const float* w2 = (const float*)d_in[6];
  const float* b2 = (const float*)d_in[7];
  const float* g2w= (const float*)d_in[8];
  const float* g2b= (const float*)d_in[9];
  const float* w3 = (const float*)d_in[10];
  const float* b3 = (const float*)d_in[11];
  const float* g3w= (const float*)d_in[12];
  const float* g3b= (const float*)d_in[13];
  const float* wb = (const float*)d_in[14];
  const float* bb = (const float*)d_in[15];
  const float* wc = (const float*)d_in[16];
  const float* bc = (const float*)d_in[17];
  float* out = (float*)d_out;

  char* ws = (char*)d_ws;
  // region A [0,64MB): xb during conv1; then h1b(32) + h2b(16) + h3(16)
  __hip_bfloat16* xb  = (__hip_bfloat16*)ws;
  __hip_bfloat16* h1b = (__hip_bfloat16*)ws;
  __hip_bfloat16* h2b = (__hip_bfloat16*)(ws + (size_t)(32<<20));
  float*          h3  = (float*)         (ws + (size_t)(48<<20));
  // region B [64,128MB): c1(64); then c2(32)+c3(16)
  float* c1 = (float*)(ws + (size_t)(64<<20));
  float* c2 = c1;
  float* c3 = (float*)(ws + (size_t)(96<<20));
  // packed weights + small buffers at 128MB
  __hip_bfloat16* wp1 = (__hip_bfloat16*)(ws + (size_t)(128<<20));
  __hip_bfloat16* wp2 = wp1 + 9*256*512;
  __hip_bfloat16* wp3 = wp2 + 9*128*256;
  char* tail = (char*)(wp3 + 9*64*128);
  float* mv     = (float*)tail;                 // 64 floats
  float* partS  = mv + 64;                      // 64 (layer offs 0/32/48)
  float* partSS = partS + 64;                   // 64
  float* sums   = partSS + 64;                  // 5120
  float* counts = sums + 5120;                  // 80

  // zero atomic accumulators (partS, partSS, sums are contiguous: 5248 floats)
  zero_k<<<21, 256, 0, stream>>>(partS, 64 + 64 + 5120);

  x_to_nhwc_k<<<16384, 256, 0, stream>>>(x, xb);
  pack_w_k<256,512><<<4608, 256, 0, stream>>>(w1, wp1);
  pack_w_k<128,256><<<1152, 256, 0, stream>>>(w2, wp2);
  pack_w_k< 64,128><<< 288, 256, 0, stream>>>(w3, wp3);

  // layer 1: 512 -> 256, GN(8 groups, cpg 32). 128co/block, 512 blocks
  conv_mfma_k<512,256,32,4><<<dim3(256,2), 512, 0, stream>>>(
      xb, wp1, b1, c1, partS, partSS);
  gn_final_k<<<1, 64, 0, stream>>>(partS, partSS, mv, 32, 1.f/(32.f*HW));
  gn_apply_k<256,32,true><<<16384, 256, 0, stream>>>(c1, mv, g1w, g1b, h1b);

  // layer 2: 256 -> 128, GN(4 groups, cpg 32). 128co/block, 256 blocks
  conv_mfma_k<256,128,32,4><<<dim3(256,1), 512, 0, stream>>>(
      h1b, wp2, b2, c2, partS + 32, partSS + 32);
  gn_final_k<<<1, 64, 0, stream>>>(partS + 32, partSS + 32, mv, 16, 1.f/(32.f*HW));
  gn_apply_k<128,32,true><<<8192, 256, 0, stream>>>(c2, mv, g2w, g2b, h2b);

  // layer 3: 128 -> 64, GN(4 groups, cpg 16); fp32 out. 64co/block (MT=2)
  conv_mfma_k<128,64,16,2><<<dim3(256,1), 512, 0, stream>>>(
      h2b, wp3, b3, c3, partS + 48, partSS + 48);
  gn_final_k<<<1, 64, 0, stream>>>(partS + 48, partSS + 48, mv, 16, 1.f/(16.f*HW));
  gn_apply_k<64,16,false><<<4096, 256, 0, stream>>>(c3, mv, g3w, g3b, h3);

  // pooling + heads
  pool_counts_k<<<BATCH, 256, 0, stream>>>(masks, counts);
  pool_sums_k<<<BATCH*32, 256, 0, stream>>>(h3, masks, sums);
  heads_k<<<BATCH*KIDS, 64, 0, stream>>>(sums, counts, wb, bb, wc, bc, out);
}

// Round 7
// 697.567 us; speedup vs baseline: 1.0720x; 1.0720x over previous
//
#include <hip/hip_runtime.h>
#include <hip/hip_bf16.h>
#include <math.h>

#define HW 16384      // 128*128
#define BATCH 4
#define KIDS 20

using short8 = __attribute__((ext_vector_type(8))) short;  // 8 bf16 = 16B
using f32x4  = __attribute__((ext_vector_type(4))) float;

__device__ __forceinline__ unsigned short bfbits(float f) {
  __hip_bfloat16 h = __float2bfloat16(f);
  return *(unsigned short*)&h;
}

// async global -> LDS, 16B per lane, wave-uniform LDS base + lane*16
__device__ __forceinline__ void gload_lds16(const void* g, void* l) {
  __builtin_amdgcn_global_load_lds(
      (const __attribute__((address_space(1))) void*)g,
      (__attribute__((address_space(3))) void*)l, 16, 0, 0);
}

__global__ __launch_bounds__(256) void zero_k(float* __restrict__ p, int n) {
  int i = blockIdx.x*256 + threadIdx.x;
  if (i < n) p[i] = 0.f;
}

// ---- x: fp32 NCHW [4][512][128][128] -> bf16 NHWC [4][16384][512] ----------
__global__ __launch_bounds__(256) void x_to_nhwc_k(const float* __restrict__ in,
                                                   __hip_bfloat16* __restrict__ out)
{
  __shared__ float tile[32][65];
  int t = blockIdx.x;
  const int pxt = t & 255; t >>= 8;
  const int ct  = t & 15;  t >>= 4;
  const int b   = t;
  const int tid = threadIdx.x;
  #pragma unroll
  for (int it = 0; it < 8; ++it) {
    int idx = tid + it*256;
    int px_l = idx & 63, c_l = idx >> 6;
    tile[c_l][px_l] = in[((size_t)(b*512 + ct*32 + c_l))*HW + pxt*64 + px_l];
  }
  __syncthreads();
  #pragma unroll
  for (int it = 0; it < 4; ++it) {
    int idx = tid + it*256;
    int c2 = idx & 15, px_l = idx >> 4;
    unsigned u = ((unsigned)bfbits(tile[c2*2+1][px_l]) << 16) | bfbits(tile[c2*2][px_l]);
    *(unsigned*)(out + ((size_t)(b*HW + pxt*64 + px_l))*512 + ct*32 + c2*2) = u;
  }
}

// ---- weights: fp32 [Co][Ci][3][3] -> bf16 [9][Co][Ci] ----------------------
template<int Co, int Ci>
__global__ __launch_bounds__(256) void pack_w_k(const float* __restrict__ w,
                                                __hip_bfloat16* __restrict__ out)
{
  const int i = blockIdx.x*256 + threadIdx.x;
  const int ci = i & (Ci-1);
  const int r  = i >> __builtin_ctz(Ci);
  const int co = r & (Co-1);
  const int t  = r >> __builtin_ctz(Co);
  out[i] = __float2bfloat16(w[((size_t)co*Ci + ci)*9 + t]);
}

// ---- conv1: WIDE-TILE implicit-GEMM conv3x3 + fused GN partials ------------
// 512 threads = 8 waves = 4 rows x 2 co-halves. Wave = 1 row x 128 px x 64 co
// (MT=4, NT=8): per tap 12 ds_read_b128 -> 32 MFMA (0.375 reads/unit, was 0.5).
// LDS single-buffered: input 6 rows x 10 segs x 1KB (q-major conflict-free
// units, segs 0/9 = zeroed px pads) + weights 9 taps x 8 co-segs x 1KB.
// Per chunk: stage W+I via gload_lds, __syncthreads (vmcnt0 drain), 9-tap
// compute (pure LDS+MFMA, compiler-scheduled), raw barrier before overwrite.
// OOB rows -> trash seg; their LDS rows stay zero from the prologue.
template<int Ci, int Co, int CPG>
__global__ __launch_bounds__(512, 2) void conv_wide_k(
    const __hip_bfloat16* __restrict__ xin,  // NHWC bf16 [4][16384][Ci]
    const __hip_bfloat16* __restrict__ wpk,  // [9][Co][Ci] bf16
    const float* __restrict__ bias,
    float* __restrict__ out,                 // NHWC fp32 [4][16384][Co]
    float* __restrict__ partS, float* __restrict__ partSS)
{
  constexpr int MT = 4, NT = 8;
  constexpr int NC  = Ci/32;
  constexpr int WCO = 128;             // co per block
  constexpr int NGW = 64/CPG;          // GN groups per wave co-range
  constexpr int IBs = 6*10*512;        // input shorts
  constexpr int WLs = 9*(WCO/16)*512;  // weight shorts
  __shared__ __align__(16) short lds[IBs + WLs + 512];
  short* const wlds  = lds + IBs;
  short* const trash = lds + IBs + WLs;

  const int bx = blockIdx.x;           // b*32 + r0g
  const int b  = bx >> 5;
  const int r0 = (bx & 31) * 4;
  const int co0 = blockIdx.y * WCO;
  const int tid = threadIdx.x;
  const int wave = tid >> 6, lane = tid & 63;
  const int row_w = wave & 3;
  const int coh   = wave >> 2;
  const int y = r0 + row_w;
  const int lr = lane & 15, q = lane >> 4;
  const int ls = lane & 15, lq = lane >> 4;   // staging: lane = lq*16 + ls

  // prologue zeroing: px-pad segs (0,9) of all 6 rows; OOB rows fully
  {
    short8 z = {0,0,0,0,0,0,0,0};
    for (int i = tid; i < 12*64; i += 512) {
      int u = i >> 6, m = i & 63;
      int r = u >> 1, side = u & 1;
      *((short8*)(lds + r*5120 + side*9*512) + m) = z;
    }
    if (r0 == 0)
      for (int i = tid; i < 640; i += 512) *((short8*)lds + i) = z;          // row 0
    if (r0 == 124)
      for (int i = tid; i < 640; i += 512) *((short8*)(lds + 5*5120) + i) = z; // row 5
  }

  const size_t in_base = (size_t)b * HW * Ci;

  // input: 6 gload_lds per wave per chunk (48 units = 6 rows x 8 segs)
  auto stage_i = [&](int ci0) {
    #pragma unroll
    for (int j = 0; j < 6; ++j) {
      int u = wave*6 + j;
      int r = u >> 3, seg = u & 7;
      int yy = r0 + r - 1;
      bool ok = (unsigned)yy < 128u;
      const __hip_bfloat16* src = xin + in_base
          + (size_t)((ok ? yy : 0)*128 + seg*16 + ls)*Ci + ci0 + lq*8;
      short* dst = ok ? (lds + (r*10 + seg + 1)*512) : trash;
      gload_lds16(src, dst);
    }
  };
  // weights: 9 gload_lds per wave (72 units; wave = co-seg, j = tap)
  auto stage_w = [&](int ci0) {
    #pragma unroll
    for (int j = 0; j < 9; ++j) {
      gload_lds16(wpk + ((size_t)(j*Co + co0 + wave*16 + ls))*Ci + ci0 + lq*8,
                  wlds + (j*8 + wave)*512);
    }
  };

  // per-lane ds_read bases (shorts)
  int base_dx[3];
  #pragma unroll
  for (int dx = 0; dx < 3; ++dx) {
    int e = dx + 15 + lr;              // slot = nt*16 + e
    base_dx[dx] = row_w*5120 + (e>>4)*512 + (e&15)*8 + q*128;
  }
  const int base_a = coh*4*512 + q*128 + lr*8;

  f32x4 acc[MT][NT] = {};
  __syncthreads();                     // zeros visible before first stage
  for (int c = 0; c < NC; ++c) {
    const int ci0 = c*32;
    stage_w(ci0);
    stage_i(ci0);
    __syncthreads();                   // drains vmcnt(0): W + I ready
    #pragma unroll
    for (int t = 0; t < 9; ++t) {
      const int dy = t/3, dx = t%3;
      short8 af[MT], bf[NT];
      #pragma unroll
      for (int mt = 0; mt < MT; ++mt)
        af[mt] = *(const short8*)(wlds + t*4096 + base_a + mt*512);
      #pragma unroll
      for (int nt = 0; nt < NT; ++nt)
        bf[nt] = *(const short8*)(lds + base_dx[dx] + dy*5120 + nt*512);
      #pragma unroll
      for (int mt = 0; mt < MT; ++mt)
        #pragma unroll
        for (int nt = 0; nt < NT; ++nt)
          acc[mt][nt] = __builtin_amdgcn_mfma_f32_16x16x32_bf16(
              af[mt], bf[nt], acc[mt][nt], 0, 0, 0);
    }
    __builtin_amdgcn_sched_barrier(0); // keep reads above the barrier
    __builtin_amdgcn_s_barrier();      // all waves done reading before overwrite
  }

  // epilogue: +bias, store, GN partials
  float sg[NGW] = {}, ssg[NGW] = {};
  #pragma unroll
  for (int mt = 0; mt < MT; ++mt) {
    const int g = (mt*16) / CPG;
    #pragma unroll
    for (int nt = 0; nt < NT; ++nt) {
      int px = nt*16 + lr;
      int co = co0 + coh*64 + mt*16 + q*4;
      const float4 bv = *(const float4*)(bias + co);
      f32x4 v = acc[mt][nt];
      v[0] += bv.x; v[1] += bv.y; v[2] += bv.z; v[3] += bv.w;
      sg[g]  += v[0] + v[1] + v[2] + v[3];
      ssg[g] += v[0]*v[0] + v[1]*v[1] + v[2]*v[2] + v[3]*v[3];
      *(f32x4*)(out + ((size_t)(b*HW + y*128 + px))*Co + co) = v;
    }
  }
  const int bgbase = b*(Co/CPG) + (co0 + coh*64)/CPG;
  #pragma unroll
  for (int g = 0; g < NGW; ++g) {
    float s = sg[g], ss = ssg[g];
    #pragma unroll
    for (int off = 32; off; off >>= 1) {
      s  += __shfl_xor(s, off);
      ss += __shfl_xor(ss, off);
    }
    if (lane == 0) {
      atomicAdd(&partS[bgbase + g], s);
      atomicAdd(&partSS[bgbase + g], ss);
    }
  }
}

// ---- conv2/conv3: r6 template (q-major, race-fixed), unchanged -------------
template<int Ci, int Co, int CPG, int MT>
__global__ __launch_bounds__(512, 2) void conv_mfma_k(
    const __hip_bfloat16* __restrict__ xin,
    const __hip_bfloat16* __restrict__ wpk,
    const float* __restrict__ bias,
    float* __restrict__ out,
    float* __restrict__ partS, float* __restrict__ partSS)
{
  constexpr int NT  = 4;
  constexpr int RG  = 64;
  constexpr int NC  = Ci/32;
  constexpr int NGW = (MT*16)/CPG;
  constexpr int WCO = 2*MT*16;
  constexpr int WSEG = WCO/16;
  constexpr int IBs = 4*10*512;
  constexpr int WLs = 9*WSEG*512;
  __shared__ __align__(16) short lds[2*IBs + WLs + 512];
  short* const wlds  = lds + 2*IBs;
  short* const trash = lds + 2*IBs + WLs;

  const int b  = blockIdx.x / RG;
  const int r0 = (blockIdx.x % RG) * 2;
  const int co0 = blockIdx.y * WCO;
  const int tid = threadIdx.x;
  const int wave = tid >> 6, lane = tid & 63;
  const int row_w = wave & 1;
  const int pw    = (wave >> 1) & 1;
  const int coh   = wave >> 2;
  const int co_w  = co0 + coh*MT*16;
  const int y = r0 + row_w;
  const int lr = lane & 15, q = lane >> 4;
  const int ls = lane & 15, lq = lane >> 4;

  {
    short8 z = {0,0,0,0,0,0,0,0};
    for (int i = tid; i < 1024; i += 512) {
      int u = i >> 6, m = i & 63;
      int buf = u >> 3, r = (u >> 1) & 3, side = u & 1;
      *((short8*)(lds + buf*IBs + r*5120 + side*9*512) + m) = z;
    }
    if (r0 == 0) {
      for (int i = tid; i < 2*640; i += 512) {
        int buf = i / 640, m = i % 640;
        *((short8*)(lds + buf*IBs) + m) = z;
      }
    }
    if (r0 == 126) {
      for (int i = tid; i < 2*640; i += 512) {
        int buf = i / 640, m = i % 640;
        *((short8*)(lds + buf*IBs + 3*5120) + m) = z;
      }
    }
  }

  const size_t in_base = (size_t)b * HW * Ci;

  auto stage_i = [&](int buf, int ci0) {
    #pragma unroll
    for (int it = 0; it < 4; ++it) {
      int gi = wave*4 + it;
      int r = gi >> 3, sd = (gi & 7) + 1;
      int yy = r0 + r - 1;
      bool ok = (unsigned)yy < 128u;
      int yc = ok ? yy : 0;
      const __hip_bfloat16* src = xin + in_base
          + (size_t)(yc*128 + (sd-1)*16 + ls)*Ci + ci0 + lq*8;
      short* dst = ok ? (lds + buf*IBs + r*5120 + sd*512) : trash;
      gload_lds16(src, dst);
    }
  };
  auto stage_w = [&](int ci0) {
    for (int u = wave; u < 9*WSEG; u += 8) {
      int t = u / WSEG, cs = u % WSEG;
      gload_lds16(wpk + ((size_t)(t*Co + co0 + cs*16 + ls))*Ci + ci0 + lq*8,
                  wlds + u*512);
    }
  };

  int base_dx[3];
  #pragma unroll
  for (int dx = 0; dx < 3; ++dx) {
    int e = dx + 15 + lr;
    base_dx[dx] = row_w*5120 + pw*2048 + (e>>4)*512 + (e&15)*8 + q*128;
  }
  const int base_a = coh*MT*512 + q*128 + lr*8;

  f32x4 acc[MT][NT] = {};
  stage_i(0, 0);
  __syncthreads();
  int cur = 0;
  for (int c = 0; c < NC; ++c) {
    const int ci0 = c*32;
    stage_w(ci0);
    if (c+1 < NC) {
      stage_i(cur^1, ci0 + 32);
      asm volatile("s_waitcnt vmcnt(4)" ::: "memory");
    } else {
      asm volatile("s_waitcnt vmcnt(0)" ::: "memory");
    }
    __builtin_amdgcn_s_barrier();
    const short* ib = lds + cur*IBs;
    #pragma unroll
    for (int t = 0; t < 9; ++t) {
      const int dy = t/3, dx = t%3;
      short8 af[MT], bf[NT];
      #pragma unroll
      for (int mt = 0; mt < MT; ++mt)
        af[mt] = *(const short8*)(wlds + t*WSEG*512 + base_a + mt*512);
      #pragma unroll
      for (int nt = 0; nt < NT; ++nt)
        bf[nt] = *(const short8*)(ib + base_dx[dx] + dy*5120 + nt*512);
      #pragma unroll
      for (int mt = 0; mt < MT; ++mt)
        #pragma unroll
        for (int nt = 0; nt < NT; ++nt)
          acc[mt][nt] = __builtin_amdgcn_mfma_f32_16x16x32_bf16(
              af[mt], bf[nt], acc[mt][nt], 0, 0, 0);
    }
    __builtin_amdgcn_sched_barrier(0);
    __builtin_amdgcn_s_barrier();
    cur ^= 1;
  }

  float sg[NGW] = {}, ssg[NGW] = {};
  #pragma unroll
  for (int mt = 0; mt < MT; ++mt) {
    const int g = (mt*16) / CPG;
    #pragma unroll
    for (int nt = 0; nt < NT; ++nt) {
      int px = pw*64 + nt*16 + lr;
      int co = co_w + mt*16 + q*4;
      const float4 bv = *(const float4*)(bias + co);
      f32x4 v = acc[mt][nt];
      v[0] += bv.x; v[1] += bv.y; v[2] += bv.z; v[3] += bv.w;
      sg[g]  += v[0] + v[1] + v[2] + v[3];
      ssg[g] += v[0]*v[0] + v[1]*v[1] + v[2]*v[2] + v[3]*v[3];
      *(f32x4*)(out + ((size_t)(b*HW + y*128 + px))*Co + co) = v;
    }
  }
  const int bgbase = b*(Co/CPG) + co_w/CPG;
  #pragma unroll
  for (int g = 0; g < NGW; ++g) {
    float s = sg[g], ss = ssg[g];
    #pragma unroll
    for (int off = 32; off; off >>= 1) {
      s  += __shfl_xor(s, off);
      ss += __shfl_xor(ss, off);
    }
    if (lane == 0) {
      atomicAdd(&partS[bgbase + g], s);
      atomicAdd(&partSS[bgbase + g], ss);
    }
  }
}

// ---- GN finalize ------------------------------------------------------------
__global__ void gn_final_k(const float* __restrict__ partS,
                           const float* __restrict__ partSS,
                           float* __restrict__ mv, int nbg, float inv_n)
{
  const int i = threadIdx.x;
  if (i < nbg) {
    float s = partS[i], ss = partSS[i];
    float mean = s*inv_n, var = ss*inv_n - mean*mean;
    mv[2*i] = mean; mv[2*i+1] = rsqrtf(var + 1e-5f);
  }
}

// ---- GN apply ---------------------------------------------------------------
template<int C, int CPG, bool BF16OUT>
__global__ __launch_bounds__(256) void gn_apply_k(const float* __restrict__ in,
    const float* __restrict__ mv, const float* __restrict__ gw,
    const float* __restrict__ gb, void* __restrict__ outp)
{
  constexpr int C4 = C/4;
  constexpr int G = C/CPG;
  const int i = blockIdx.x*256 + threadIdx.x;
  const int c4 = i & (C4-1);
  const int pxb = i >> __builtin_ctz(C4);
  const int b = pxb >> 14;
  const int c = c4*4;
  const int bg = b*G + c/CPG;
  const float mean = mv[2*bg], inv = mv[2*bg+1];
  float4 v = *((const float4*)in + i);
  const float4 w4 = *(const float4*)(gw + c);
  const float4 b4 = *(const float4*)(gb + c);
  float r0 = fmaxf((v.x-mean)*inv*w4.x + b4.x, 0.f);
  float r1 = fmaxf((v.y-mean)*inv*w4.y + b4.y, 0.f);
  float r2 = fmaxf((v.z-mean)*inv*w4.z + b4.z, 0.f);
  float r3 = fmaxf((v.w-mean)*inv*w4.w + b4.w, 0.f);
  if (BF16OUT) {
    uint2 o;
    o.x = ((unsigned)bfbits(r1) << 16) | bfbits(r0);
    o.y = ((unsigned)bfbits(r3) << 16) | bfbits(r2);
    *(uint2*)((__hip_bfloat16*)outp + (size_t)i*4) = o;
  } else {
    *((float4*)outp + i) = make_float4(r0,r1,r2,r3);
  }
}

// ---- pooling ----------------------------------------------------------------
__global__ __launch_bounds__(256) void pool_counts_k(
    const int* __restrict__ masks, float* __restrict__ counts)
{
  __shared__ int hist[KIDS];
  const int b = blockIdx.x;
  if (threadIdx.x < KIDS) hist[threadIdx.x] = 0;
  __syncthreads();
  for (int p = threadIdx.x; p < HW; p += 256) {
    const int m = masks[b*HW + p];
    if (m > 0) atomicAdd(&hist[m-1], 1);
  }
  __syncthreads();
  if (threadIdx.x < KIDS) counts[b*KIDS + threadIdx.x] = (float)hist[threadIdx.x];
}

__global__ __launch_bounds__(256) void pool_sums_k(const float* __restrict__ h3,
    const int* __restrict__ masks, float* __restrict__ sums)
{
  __shared__ float acc[KIDS*64];
  const int b = blockIdx.x >> 5, chunk = blockIdx.x & 31;
  const int tid = threadIdx.x;
  for (int j = tid; j < KIDS*64; j += 256) acc[j] = 0.f;
  __syncthreads();
  const int ch = tid & 63, pi = tid >> 6;
  const int p0 = chunk*512;
  for (int p = p0 + pi; p < p0 + 512; p += 4) {
    int m = masks[b*HW + p];
    if (m > 0) atomicAdd(&acc[(m-1)*64 + ch], h3[((size_t)(b*HW + p))*64 + ch]);
  }
  __syncthreads();
  for (int j = tid; j < KIDS*64; j += 256) atomicAdd(&sums[b*KIDS*64 + j], acc[j]);
}

// ---- heads ------------------------------------------------------------------
__global__ __launch_bounds__(64) void heads_k(
    const float* __restrict__ sums, const float* __restrict__ counts,
    const float* __restrict__ wb, const float* __restrict__ bb,
    const float* __restrict__ wc, const float* __restrict__ bc,
    float* __restrict__ out)
{
  const int bk = blockIdx.x;
  const int c = threadIdx.x;
  const float pooled = sums[bk*64 + c] / (counts[bk] + 1e-6f);
  #pragma unroll
  for (int o = 0; o < 7; ++o) {
    float t = pooled * wb[o*64 + c];
    for (int off = 32; off > 0; off >>= 1) t += __shfl_down(t, off);
    if (c == 0) out[bk*7 + o] = t + bb[o];
  }
  float t = pooled * wc[c];
  for (int off = 32; off > 0; off >>= 1) t += __shfl_down(t, off);
  if (c == 0) out[BATCH*KIDS*7 + bk] = 1.f / (1.f + expf(-(t + bc[0])));
}

extern "C" void kernel_launch(void* const* d_in, const int* in_sizes, int n_in,
                              void* d_out, int out_size, void* d_ws, size_t ws_size,
                              hipStream_t stream)
{
  const float* x     = (const float*)d_in[0];
  const int*   masks = (const int*)  d_in[1];
  const float* w1 = (const float*)d_in[2];
  const float* b1 = (const float*)d_in[3];
  const float* g1w= (const float*)d_in[4];
  const float* g1b= (const float*)d_in[5];
  const float* w2 = (const float*)d_in[6];
  const float* b2 = (const float*)d_in[7];
  const float* g2w= (const float*)d_in[8];
  const float* g2b= (const float*)d_in[9];
  const float* w3 = (const float*)d_in[10];
  const float* b3 = (const float*)d_in[11];
  const float* g3w= (const float*)d_in[12];
  const float* g3b= (const float*)d_in[13];
  const float* wb = (const float*)d_in[14];
  const float* bb = (const float*)d_in[15];
  const float* wc = (const float*)d_in[16];
  const float* bc = (const float*)d_in[17];
  float* out = (float*)d_out;

  char* ws = (char*)d_ws;
  __hip_bfloat16* xb  = (__hip_bfloat16*)ws;
  __hip_bfloat16* h1b = (__hip_bfloat16*)ws;
  __hip_bfloat16* h2b = (__hip_bfloat16*)(ws + (size_t)(32<<20));
  float*          h3  = (float*)         (ws + (size_t)(48<<20));
  float* c1 = (float*)(ws + (size_t)(64<<20));
  float* c2 = c1;
  float* c3 = (float*)(ws + (size_t)(96<<20));
  __hip_bfloat16* wp1 = (__hip_bfloat16*)(ws + (size_t)(128<<20));
  __hip_bfloat16* wp2 = wp1 + 9*256*512;
  __hip_bfloat16* wp3 = wp2 + 9*128*256;
  char* tail = (char*)(wp3 + 9*64*128);
  float* mv     = (float*)tail;
  float* partS  = mv + 64;
  float* partSS = partS + 64;
  float* sums   = partSS + 64;
  float* counts = sums + 5120;

  zero_k<<<21, 256, 0, stream>>>(partS, 64 + 64 + 5120);

  x_to_nhwc_k<<<16384, 256, 0, stream>>>(x, xb);
  pack_w_k<256,512><<<4608, 256, 0, stream>>>(w1, wp1);
  pack_w_k<128,256><<<1152, 256, 0, stream>>>(w2, wp2);
  pack_w_k< 64,128><<< 288, 256, 0, stream>>>(w3, wp3);

  // layer 1: 512 -> 256, GN(8 groups, cpg 32). wide-tile: 256 blocks, 1/CU
  conv_wide_k<512,256,32><<<dim3(128,2), 512, 0, stream>>>(
      xb, wp1, b1, c1, partS, partSS);
  gn_final_k<<<1, 64, 0, stream>>>(partS, partSS, mv, 32, 1.f/(32.f*HW));
  gn_apply_k<256,32,true><<<16384, 256, 0, stream>>>(c1, mv, g1w, g1b, h1b);

  // layer 2: 256 -> 128, GN(4 groups, cpg 32). r6 template
  conv_mfma_k<256,128,32,4><<<dim3(256,1), 512, 0, stream>>>(
      h1b, wp2, b2, c2, partS + 32, partSS + 32);
  gn_final_k<<<1, 64, 0, stream>>>(partS + 32, partSS + 32, mv, 16, 1.f/(32.f*HW));
  gn_apply_k<128,32,true><<<8192, 256, 0, stream>>>(c2, mv, g2w, g2b, h2b);

  // layer 3: 128 -> 64, GN(4 groups, cpg 16); fp32 out. r6 template
  conv_mfma_k<128,64,16,2><<<dim3(256,1), 512, 0, stream>>>(
      h2b, wp3, b3, c3, partS + 48, partSS + 48);
  gn_final_k<<<1, 64, 0, stream>>>(partS + 48, partSS + 48, mv, 16, 1.f/(16.f*HW));
  gn_apply_k<64,16,false><<<4096, 256, 0, stream>>>(c3, mv, g3w, g3b, h3);

  pool_counts_k<<<BATCH, 256, 0, stream>>>(masks, counts);
  pool_sums_k<<<BATCH*32, 256, 0, stream>>>(h3, masks, sums);
  heads_k<<<BATCH*KIDS, 64, 0, stream>>>(sums, counts, wb, bb, wc, bc, out);
}